// Round 8
// baseline (25149.019 us; speedup 1.0000x reference)
//
#include <hip/hip_runtime.h>
#include <math.h>

#define H 1024
#define D 256
#define NB 256
#define NT 512
#define LW 64   // warmup (teacher-forced) length

typedef float f32x4 __attribute__((ext_vector_type(4)));

__device__ __forceinline__ float sigf(float v) { return 1.f / (1.f + __expf(-v)); }

__device__ __forceinline__ float waveReduce(float v) {
#pragma unroll
    for (int off = 32; off > 0; off >>= 1) v += __shfl_xor(v, off, 64);
    return v;
}

// LLC-coherent accesses (sc0 sc1 bypass L1/L2) — no cache-maintenance fences needed.
__device__ __forceinline__ f32x4 ldg4_sc(const float* p) {
    f32x4 r;
    asm volatile("global_load_dwordx4 %0, %1, off sc0 sc1\n\ts_waitcnt vmcnt(0)"
                 : "=v"(r) : "v"(p) : "memory");
    return r;
}
__device__ __forceinline__ float ldg1_sc(const float* p) {
    float r;
    asm volatile("global_load_dword %0, %1, off sc0 sc1\n\ts_waitcnt vmcnt(0)"
                 : "=v"(r) : "v"(p) : "memory");
    return r;
}
__device__ __forceinline__ void stg4_sc(float* p, f32x4 v) {
    asm volatile("global_store_dwordx4 %0, %1, off sc0 sc1" :: "v"(p), "v"(v) : "memory");
}
__device__ __forceinline__ void stg1_sc(float* p, float v) {
    asm volatile("global_store_dword %0, %1, off sc0 sc1" :: "v"(p), "v"(v) : "memory");
}

// Fused readiness+data: values are |v|<=1; producer stores v+offset where
// offset = 8*(step&3)-12 in {-12,-4,4,12}. Consumer polls until ALL words sit
// in the expected region (distance >= 8 between adjacent regions, threshold 2
// => stale/zero/torn data can never false-positive), then unbiases.
__device__ __forceinline__ f32x4 pollLoad4(const float* p, float off) {
    f32x4 r;
    for (;;) {
        r = ldg4_sc(p);
        float m = fmaxf(fmaxf(fabsf(r.x - off), fabsf(r.y - off)),
                        fmaxf(fabsf(r.z - off), fabsf(r.w - off)));
        if (m < 2.0f) break;
        __builtin_amdgcn_s_sleep(1);
    }
    r.x -= off; r.y -= off; r.z -= off; r.w -= off;
    return r;
}
__device__ __forceinline__ float pollLoad1(const float* p, float off) {
    float r;
    for (;;) {
        r = ldg1_sc(p);
        if (fabsf(r - off) < 2.0f) break;
        __builtin_amdgcn_s_sleep(1);
    }
    return r - off;
}

// ---- workspace layout (floats) ----
// [0 .. 2H)    hg0 ping-pong  [2][H]   (layer-0 h exchange)
// [2H .. 4H)   hg1 ping-pong
// [4H .. 6H)   hg2 ping-pong
// [6H .. 6H+D) inp vector
__global__ void ws_clear(float* ws) {
    for (int i = threadIdx.x; i < 6 * H + D; i += blockDim.x) ws[i] = 0.f;
}

__global__ __launch_bounds__(NT, 2) void rnn_reg5(
    const float* __restrict__ x, const float* __restrict__ h0in, const float* __restrict__ c0,
    const float* __restrict__ Wih0, const float* __restrict__ Whh0,
    const float* __restrict__ Wih1, const float* __restrict__ Whh1,
    const float* __restrict__ Wih2, const float* __restrict__ Whh2,
    const float* __restrict__ b_ih, const float* __restrict__ b_hh,
    const float* __restrict__ Wfc, const float* __restrict__ bfc,
    float* __restrict__ out, float* __restrict__ ws,
    int T, int L)
{
    const int b = blockIdx.x;
    const int tid = threadIdx.x;
    const int w = tid >> 6;
    const int lane = tid & 63;
    const int gate = w & 3;          // i,f,g,o
    const int up = w >> 2;           // 0..1 -> unit pair
    const int u0 = b * 4 + 2 * up;
    const int r0 = gate * H + u0;
    const int r1 = r0 + 1;
    const int off = lane * 4;

    float* hg0 = ws;
    float* hg1 = ws + 2 * H;
    float* hg2 = ws + 4 * H;
    float* inp = ws + 6 * H;

    __shared__ float lds_h0[2 * H], lds_h1[2 * H], lds_h2[2 * H];
    __shared__ float lds_fc[H];
    __shared__ float lds_inp[D];
    __shared__ float lds_x[LW];
    __shared__ float gate_buf[16];
    __shared__ float red[8];
    __shared__ float c_st[12];

    // ---- one-time: weights -> registers (2 rows/wave, 42 float4) ----
    float4 wA0[5], wB0[5], wA1[8], wB1[8], wA2[8], wB2[8];
    wA0[0] = *(const float4*)(Wih0 + (size_t)r0 * 256 + off);
    wB0[0] = *(const float4*)(Wih0 + (size_t)r1 * 256 + off);
#pragma unroll
    for (int j = 0; j < 4; ++j) {
        wA0[j + 1] = *(const float4*)(Whh0 + (size_t)r0 * H + j * 256 + off);
        wB0[j + 1] = *(const float4*)(Whh0 + (size_t)r1 * H + j * 256 + off);
        wA1[j]     = *(const float4*)(Wih1 + (size_t)r0 * H + j * 256 + off);
        wB1[j]     = *(const float4*)(Wih1 + (size_t)r1 * H + j * 256 + off);
        wA1[j + 4] = *(const float4*)(Whh1 + (size_t)r0 * H + j * 256 + off);
        wB1[j + 4] = *(const float4*)(Whh1 + (size_t)r1 * H + j * 256 + off);
        wA2[j]     = *(const float4*)(Wih2 + (size_t)r0 * H + j * 256 + off);
        wB2[j]     = *(const float4*)(Wih2 + (size_t)r1 * H + j * 256 + off);
        wA2[j + 4] = *(const float4*)(Whh2 + (size_t)r0 * H + j * 256 + off);
        wB2[j + 4] = *(const float4*)(Whh2 + (size_t)r1 * H + j * 256 + off);
    }
    const float bA0 = b_ih[r0] + b_hh[r0];
    const float bB0 = b_ih[r1] + b_hh[r1];
    const float bA1 = b_ih[4 * H + r0] + b_hh[4 * H + r0];
    const float bB1 = b_ih[4 * H + r1] + b_hh[4 * H + r1];
    const float bA2 = b_ih[8 * H + r0] + b_hh[8 * H + r0];
    const float bB2 = b_ih[8 * H + r1] + b_hh[8 * H + r1];
    const float bfc_b = bfc[b];

#define KA(v) asm volatile("" : "+v"(v.x), "+v"(v.y), "+v"(v.z), "+v"(v.w))
#pragma unroll
    for (int j = 0; j < 5; ++j) { KA(wA0[j]); KA(wB0[j]); }
#pragma unroll
    for (int j = 0; j < 8; ++j) { KA(wA1[j]); KA(wB1[j]); KA(wA2[j]); KA(wB2[j]); }
#undef KA

    // ---- prologue: initial states into LDS slot 1 (read by step 0) ----
    for (int i = tid; i < H; i += NT) {
        lds_fc[i]     = Wfc[(size_t)b * H + i];
        lds_h0[H + i] = h0in[i];
        lds_h1[H + i] = h0in[H + i];
        lds_h2[H + i] = h0in[2 * H + i];
    }
    if (tid < LW && tid < L) lds_x[tid] = x[(size_t)b * L + tid];
    if (tid < 12) c_st[tid] = c0[(tid >> 2) * H + b * 4 + (tid & 3)];
    if (tid == 0) {
        float v = x[(size_t)b * L];
        out[(size_t)b * T] = v;                       // out column 0
        stg1_sc(inp + b, v + (8.0f * 0 - 12.0f));     // "D(-1)" store, tag idx 0
    }
    __syncthreads();

#define DOT(WA, WB, N1, P1, N2, P2, BA, BB)                                   \
    {                                                                         \
        float4 a0 = {0,0,0,0}, a1 = {0,0,0,0};                                \
        _Pragma("unroll")                                                     \
        for (int j = 0; j < N1; ++j) {                                        \
            float4 v = *(const float4*)((P1) + j * 256 + off);                \
            a0.x += WA[j].x*v.x; a0.y += WA[j].y*v.y;                         \
            a0.z += WA[j].z*v.z; a0.w += WA[j].w*v.w;                         \
            a1.x += WB[j].x*v.x; a1.y += WB[j].y*v.y;                         \
            a1.z += WB[j].z*v.z; a1.w += WB[j].w*v.w;                         \
        }                                                                     \
        _Pragma("unroll")                                                     \
        for (int j = 0; j < N2; ++j) {                                        \
            float4 v = *(const float4*)((P2) + j * 256 + off);                \
            a0.x += WA[N1+j].x*v.x; a0.y += WA[N1+j].y*v.y;                   \
            a0.z += WA[N1+j].z*v.z; a0.w += WA[N1+j].w*v.w;                   \
            a1.x += WB[N1+j].x*v.x; a1.y += WB[N1+j].y*v.y;                   \
            a1.z += WB[N1+j].z*v.z; a1.w += WB[N1+j].w*v.w;                   \
        }                                                                     \
        float s0 = waveReduce(a0.x + a0.y + a0.z + a0.w);                     \
        float s1 = waveReduce(a1.x + a1.y + a1.z + a1.w);                     \
        if (lane == 0) {                                                      \
            gate_buf[(2*up)*4 + gate]   = s0 + BA;                            \
            gate_buf[(2*up+1)*4 + gate] = s1 + BB;                            \
        }                                                                     \
    }

    // wave 7 combines gates, packs the block's 4 h values + region tag into ONE
    // 16B store (fire-and-forget), and mirrors them into own LDS slot.
#define COMBINE(LIDX, HGPTR, LDSPTR)                                          \
    if (w == 7) {                                                             \
        float hn = 0.f;                                                       \
        if (lane < 4) {                                                       \
            float gi = gate_buf[lane*4+0], gf = gate_buf[lane*4+1];           \
            float gg = gate_buf[lane*4+2], go = gate_buf[lane*4+3];           \
            float cn = sigf(gf)*c_st[(LIDX)*4+lane] + sigf(gi)*tanhf(gg);     \
            c_st[(LIDX)*4+lane] = cn;                                         \
            hn = sigf(go)*tanhf(cn);                                          \
        }                                                                     \
        float v0=__shfl(hn,0), v1=__shfl(hn,1), v2=__shfl(hn,2), v3=__shfl(hn,3); \
        if (lane == 0) {                                                      \
            f32x4 pk = {v0+tagS, v1+tagS, v2+tagS, v3+tagS};                  \
            stg4_sc((HGPTR) + b*4, pk);                                       \
            float4 raw = {v0, v1, v2, v3};                                    \
            *(float4*)((LDSPTR) + b*4) = raw;                                 \
        }                                                                     \
    }

    for (int s = 0; s < T - 1; ++s) {
        const int ps = s & 1;                       // fresh slot this step
        const float tagS = 8.0f * (s & 3) - 12.0f;  // region for step-s products

        // ---------- phase A: layer 0 ----------
        if (tid < 256 && tid != b) lds_inp[tid] = pollLoad1(inp + tid, tagS);
        __syncthreads();
        DOT(wA0, wB0, 1, lds_inp, 4, lds_h0 + (ps ^ 1) * H, bA0, bB0)
        __syncthreads();
        COMBINE(0, hg0 + ps * H, lds_h0 + ps * H)

        // ---------- phase B: layer 1 ----------
        if (tid < 256 && tid != b) {
            f32x4 v = pollLoad4(hg0 + ps * H + tid * 4, tagS);
            *(f32x4*)(lds_h0 + ps * H + tid * 4) = v;
        }
        __syncthreads();
        DOT(wA1, wB1, 4, lds_h0 + ps * H, 4, lds_h1 + (ps ^ 1) * H, bA1, bB1)
        __syncthreads();
        COMBINE(1, hg1 + ps * H, lds_h1 + ps * H)

        // ---------- phase C: layer 2 ----------
        if (tid < 256 && tid != b) {
            f32x4 v = pollLoad4(hg1 + ps * H + tid * 4, tagS);
            *(f32x4*)(lds_h1 + ps * H + tid * 4) = v;
        }
        __syncthreads();
        DOT(wA2, wB2, 4, lds_h1 + ps * H, 4, lds_h2 + (ps ^ 1) * H, bA2, bB2)
        __syncthreads();
        COMBINE(2, hg2 + ps * H, lds_h2 + ps * H)

        // ---------- phase D: gather h2 (next step's recurrent) + fc ----------
        if (tid < 256 && tid != b) {
            f32x4 v = pollLoad4(hg2 + ps * H + tid * 4, tagS);
            *(f32x4*)(lds_h2 + ps * H + tid * 4) = v;
        }
        __syncthreads();
        if (s + 1 >= L) {
            float2 pv = *(const float2*)(lds_h2 + ps * H + 2 * tid);
            float2 fw = *(const float2*)(lds_fc + 2 * tid);
            float a = waveReduce(pv.x * fw.x + pv.y * fw.y);
            if (lane == 0) red[w] = a;
            __syncthreads();
        }
        if (w == 7 && lane == 0) {
            float nxt;
            if (s + 1 < L) {
                nxt = lds_x[s + 1];
            } else {
                float sfc = red[0] + red[1] + red[2] + red[3]
                          + red[4] + red[5] + red[6] + red[7];
                nxt = sigf(sfc + bfc_b);
            }
            out[(size_t)b * T + s + 1] = nxt;
            stg1_sc(inp + b, nxt + (8.0f * ((s + 1) & 3) - 12.0f));
            lds_inp[b] = nxt;   // self short-circuit for next A
        }
    }
#undef DOT
#undef COMBINE
}

extern "C" void kernel_launch(void* const* d_in, const int* in_sizes, int n_in,
                              void* d_out, int out_size, void* d_ws, size_t ws_size,
                              hipStream_t stream) {
    const float* x    = (const float*)d_in[0];
    const float* h0   = (const float*)d_in[1];
    const float* c0   = (const float*)d_in[2];
    const float* Wih0 = (const float*)d_in[3];
    const float* Whh0 = (const float*)d_in[4];
    const float* Wih1 = (const float*)d_in[5];
    const float* Whh1 = (const float*)d_in[6];
    const float* Wih2 = (const float*)d_in[7];
    const float* Whh2 = (const float*)d_in[8];
    const float* bih  = (const float*)d_in[9];
    const float* bhh  = (const float*)d_in[10];
    const float* Wfc  = (const float*)d_in[11];
    const float* bfc  = (const float*)d_in[12];

    float* out = (float*)d_out;
    float* ws  = (float*)d_ws;

    int T = out_size / D;        // 2048
    int L = in_sizes[0] / D;     // 64

    ws_clear<<<1, 512, 0, stream>>>(ws);

    void* args[] = { &x, &h0, &c0, &Wih0, &Whh0, &Wih1, &Whh1, &Wih2, &Whh2,
                     &bih, &bhh, &Wfc, &bfc, &out, &ws, &T, &L };

    (void)hipLaunchCooperativeKernel((void*)rnn_reg5, dim3(NB), dim3(NT), args, 0, stream);
}

// Round 9
// 24744.095 us; speedup vs baseline: 1.0164x; 1.0164x over previous
//
#include <hip/hip_runtime.h>
#include <math.h>

#define H 1024
#define D 256
#define NB 256
#define NT 512
#define LW 64   // warmup (teacher-forced) length

typedef float f32x4 __attribute__((ext_vector_type(4)));

__device__ __forceinline__ float sigf(float v) { return 1.f / (1.f + __expf(-v)); }

__device__ __forceinline__ float waveReduce(float v) {
#pragma unroll
    for (int off = 32; off > 0; off >>= 1) v += __shfl_xor(v, off, 64);
    return v;
}

// LLC-coherent ops (sc0 sc1 bypass L1/L2) — no cache-maintenance fences needed.
__device__ __forceinline__ f32x4 ldg4_nw(const float* p) {   // issue only, no wait
    f32x4 r;
    asm volatile("global_load_dwordx4 %0, %1, off sc0 sc1" : "=v"(r) : "v"(p) : "memory");
    return r;
}
// waitcnt with the loaded values chained through it: uses of a..d after this
// CANNOT be hoisted above the wait (true data dependence — rule-18 safe).
__device__ __forceinline__ void vm_wait4(f32x4& a, f32x4& b, f32x4& c, f32x4& d) {
    asm volatile("s_waitcnt vmcnt(0)" : "+v"(a), "+v"(b), "+v"(c), "+v"(d) :: "memory");
    __builtin_amdgcn_sched_barrier(0);
}
__device__ __forceinline__ void vm_wait1(f32x4& a) {
    asm volatile("s_waitcnt vmcnt(0)" : "+v"(a) :: "memory");
    __builtin_amdgcn_sched_barrier(0);
}
__device__ __forceinline__ void stg4_sc(float* p, f32x4 v) {
    asm volatile("global_store_dwordx4 %0, %1, off sc0 sc1" :: "v"(p), "v"(v) : "memory");
}
__device__ __forceinline__ void stg1_sc(float* p, float v) {
    asm volatile("global_store_dword %0, %1, off sc0 sc1" :: "v"(p), "v"(v) : "memory");
}

// Tags: values satisfy |v|<1; producer stores v + tag where tag = 8*(i&3)-12
// in {-12,-4,4,12}. Valid iff |x-tag| < 2. Zero / 0xAA / stale (tag distance
// >= 8) can never false-validate.
__device__ __forceinline__ float tagf(int i) { return 8.0f * (float)(i & 3) - 12.0f; }
__device__ __forceinline__ bool vld4(f32x4 c, float tg) {
    float m = fmaxf(fmaxf(fabsf(c.x - tg), fabsf(c.y - tg)),
                    fmaxf(fabsf(c.z - tg), fabsf(c.w - tg)));
    return m < 2.0f;
}

// ---- workspace layout (floats) ----
// [0 .. 2H)    hg0 ping-pong [2][H]
// [2H .. 4H)   hg1 ping-pong
// [4H .. 6H)   hg2 ping-pong
// [6H .. 6H+D) inp vector (single buffer, tag-rotated)
__global__ void ws_clear(float* ws) {
    for (int i = threadIdx.x; i < 6 * H + D; i += blockDim.x) ws[i] = 0.f;
}

__global__ __launch_bounds__(NT, 2) void rnn_reg6(
    const float* __restrict__ x, const float* __restrict__ h0in, const float* __restrict__ c0,
    const float* __restrict__ Wih0, const float* __restrict__ Whh0,
    const float* __restrict__ Wih1, const float* __restrict__ Whh1,
    const float* __restrict__ Wih2, const float* __restrict__ Whh2,
    const float* __restrict__ b_ih, const float* __restrict__ b_hh,
    const float* __restrict__ Wfc, const float* __restrict__ bfc,
    float* __restrict__ out, float* __restrict__ ws,
    int T, int L)
{
    const int b = blockIdx.x;
    const int tid = threadIdx.x;
    const int w = tid >> 6;
    const int lane = tid & 63;
    const int gate = w & 3;          // i,f,g,o
    const int up = w >> 2;           // 0..1 -> unit pair
    const int u0 = b * 4 + 2 * up;
    const int r0 = gate * H + u0;
    const int r1 = r0 + 1;
    const int off = lane * 4;

    float* hg0 = ws;
    float* hg1 = ws + 2 * H;
    float* hg2 = ws + 4 * H;
    float* inp = ws + 6 * H;

    __shared__ float lds_h0[2 * H], lds_h1[2 * H], lds_h2[2 * H];
    __shared__ float lds_fc[H];
    __shared__ float lds_inp[D];
    __shared__ float lds_x[LW];
    __shared__ float gate_buf[16];
    __shared__ float red[8];
    __shared__ float c_st[12];

    // ---- one-time: weights -> registers (2 rows/wave, 42 float4) ----
    float4 wA0[5], wB0[5], wA1[8], wB1[8], wA2[8], wB2[8];
    wA0[0] = *(const float4*)(Wih0 + (size_t)r0 * 256 + off);
    wB0[0] = *(const float4*)(Wih0 + (size_t)r1 * 256 + off);
#pragma unroll
    for (int j = 0; j < 4; ++j) {
        wA0[j + 1] = *(const float4*)(Whh0 + (size_t)r0 * H + j * 256 + off);
        wB0[j + 1] = *(const float4*)(Whh0 + (size_t)r1 * H + j * 256 + off);
        wA1[j]     = *(const float4*)(Wih1 + (size_t)r0 * H + j * 256 + off);
        wB1[j]     = *(const float4*)(Wih1 + (size_t)r1 * H + j * 256 + off);
        wA1[j + 4] = *(const float4*)(Whh1 + (size_t)r0 * H + j * 256 + off);
        wB1[j + 4] = *(const float4*)(Whh1 + (size_t)r1 * H + j * 256 + off);
        wA2[j]     = *(const float4*)(Wih2 + (size_t)r0 * H + j * 256 + off);
        wB2[j]     = *(const float4*)(Wih2 + (size_t)r1 * H + j * 256 + off);
        wA2[j + 4] = *(const float4*)(Whh2 + (size_t)r0 * H + j * 256 + off);
        wB2[j + 4] = *(const float4*)(Whh2 + (size_t)r1 * H + j * 256 + off);
    }
    const float bA0 = b_ih[r0] + b_hh[r0];
    const float bB0 = b_ih[r1] + b_hh[r1];
    const float bA1 = b_ih[4 * H + r0] + b_hh[4 * H + r0];
    const float bB1 = b_ih[4 * H + r1] + b_hh[4 * H + r1];
    const float bA2 = b_ih[8 * H + r0] + b_hh[8 * H + r0];
    const float bB2 = b_ih[8 * H + r1] + b_hh[8 * H + r1];
    const float bfc_b = bfc[b];

#define KA(v) asm volatile("" : "+v"(v.x), "+v"(v.y), "+v"(v.z), "+v"(v.w))
#pragma unroll
    for (int j = 0; j < 5; ++j) { KA(wA0[j]); KA(wB0[j]); }
#pragma unroll
    for (int j = 0; j < 8; ++j) { KA(wA1[j]); KA(wB1[j]); KA(wA2[j]); KA(wB2[j]); }
#undef KA

    // ---- prologue: initial states into LDS slot 1 (read by step 0) ----
    for (int i = tid; i < H; i += NT) {
        lds_fc[i]     = Wfc[(size_t)b * H + i];
        lds_h0[H + i] = h0in[i];
        lds_h1[H + i] = h0in[H + i];
        lds_h2[H + i] = h0in[2 * H + i];
    }
    if (tid < LW && tid < L) lds_x[tid] = x[(size_t)b * L + tid];
    if (tid < 12) c_st[tid] = c0[(tid >> 2) * H + b * 4 + (tid & 3)];
    if (tid == 0) {
        float v = x[(size_t)b * L];
        out[(size_t)b * T] = v;                 // out column 0
        stg1_sc(inp + b, v + tagf(0));          // step-0 input, tag idx 0
    }
    __syncthreads();

    // wave-0 poll+stash: 4KB tagged region -> LDS, loads double as data fetch.
#define POLLSTASH_H(SRC, DST, TG)                                              \
    if (w == 0) {                                                              \
        const float* src_ = (SRC); float* dst_ = (DST); const float tg_ = (TG);\
        bool d0 = false, d1 = false, d2 = false, d3 = false;                   \
        for (;;) {                                                             \
            f32x4 c0 = {0,0,0,0}, c1 = {0,0,0,0}, c2 = {0,0,0,0}, c3 = {0,0,0,0};\
            if (!d0) c0 = ldg4_nw(src_ + lane * 4);                            \
            if (!d1) c1 = ldg4_nw(src_ + (lane + 64) * 4);                     \
            if (!d2) c2 = ldg4_nw(src_ + (lane + 128) * 4);                    \
            if (!d3) c3 = ldg4_nw(src_ + (lane + 192) * 4);                    \
            vm_wait4(c0, c1, c2, c3);                                          \
            if (!d0 && vld4(c0, tg_)) { d0 = true;                             \
                f32x4 u = {c0.x-tg_, c0.y-tg_, c0.z-tg_, c0.w-tg_};            \
                *(f32x4*)(dst_ + lane * 4) = u; }                              \
            if (!d1 && vld4(c1, tg_)) { d1 = true;                             \
                f32x4 u = {c1.x-tg_, c1.y-tg_, c1.z-tg_, c1.w-tg_};            \
                *(f32x4*)(dst_ + (lane + 64) * 4) = u; }                       \
            if (!d2 && vld4(c2, tg_)) { d2 = true;                             \
                f32x4 u = {c2.x-tg_, c2.y-tg_, c2.z-tg_, c2.w-tg_};            \
                *(f32x4*)(dst_ + (lane + 128) * 4) = u; }                      \
            if (!d3 && vld4(c3, tg_)) { d3 = true;                             \
                f32x4 u = {c3.x-tg_, c3.y-tg_, c3.z-tg_, c3.w-tg_};            \
                *(f32x4*)(dst_ + (lane + 192) * 4) = u; }                      \
            if (__all(d0 && d1 && d2 && d3)) break;                            \
            __builtin_amdgcn_s_sleep(1);                                       \
        }                                                                      \
    }

#define DOT(WA, WB, N1, P1, N2, P2, BA, BB)                                   \
    {                                                                         \
        float4 a0 = {0,0,0,0}, a1 = {0,0,0,0};                                \
        _Pragma("unroll")                                                     \
        for (int j = 0; j < N1; ++j) {                                        \
            float4 v = *(const float4*)((P1) + j * 256 + off);                \
            a0.x += WA[j].x*v.x; a0.y += WA[j].y*v.y;                         \
            a0.z += WA[j].z*v.z; a0.w += WA[j].w*v.w;                         \
            a1.x += WB[j].x*v.x; a1.y += WB[j].y*v.y;                         \
            a1.z += WB[j].z*v.z; a1.w += WB[j].w*v.w;                         \
        }                                                                     \
        _Pragma("unroll")                                                     \
        for (int j = 0; j < N2; ++j) {                                        \
            float4 v = *(const float4*)((P2) + j * 256 + off);                \
            a0.x += WA[N1+j].x*v.x; a0.y += WA[N1+j].y*v.y;                   \
            a0.z += WA[N1+j].z*v.z; a0.w += WA[N1+j].w*v.w;                   \
            a1.x += WB[N1+j].x*v.x; a1.y += WB[N1+j].y*v.y;                   \
            a1.z += WB[N1+j].z*v.z; a1.w += WB[N1+j].w*v.w;                   \
        }                                                                     \
        float s0 = waveReduce(a0.x + a0.y + a0.z + a0.w);                     \
        float s1 = waveReduce(a1.x + a1.y + a1.z + a1.w);                     \
        if (lane == 0) {                                                      \
            gate_buf[(2*up)*4 + gate]   = s0 + BA;                            \
            gate_buf[(2*up+1)*4 + gate] = s1 + BB;                            \
        }                                                                     \
    }

    // wave 7: combine gates, pack 4 h values + tag, single fire-and-forget store.
#define COMBINE(LIDX, HGPTR, TG)                                              \
    if (w == 7) {                                                             \
        float hn = 0.f;                                                       \
        if (lane < 4) {                                                       \
            float gi = gate_buf[lane*4+0], gf = gate_buf[lane*4+1];           \
            float gg = gate_buf[lane*4+2], go = gate_buf[lane*4+3];           \
            float cn = sigf(gf)*c_st[(LIDX)*4+lane] + sigf(gi)*tanhf(gg);     \
            c_st[(LIDX)*4+lane] = cn;                                         \
            hn = sigf(go)*tanhf(cn);                                          \
        }                                                                     \
        float v0=__shfl(hn,0), v1=__shfl(hn,1), v2=__shfl(hn,2), v3=__shfl(hn,3); \
        if (lane == 0) {                                                      \
            f32x4 pk = {v0+(TG), v1+(TG), v2+(TG), v3+(TG)};                  \
            stg4_sc((HGPTR) + b*4, pk);                                       \
        }                                                                     \
    }

    for (int s = 0; s < T - 1; ++s) {
        const int ps = s & 1;
        const float tagS = tagf(s);

        // ---------- phase A: layer 0 ----------
        if (w == 0) {   // poll+stash inp (1KB, 64 chunks, 1/lane)
            bool d0 = false;
            for (;;) {
                f32x4 c0 = {0,0,0,0};
                if (!d0) c0 = ldg4_nw(inp + lane * 4);
                vm_wait1(c0);
                if (!d0 && vld4(c0, tagS)) {
                    d0 = true;
                    f32x4 u = {c0.x-tagS, c0.y-tagS, c0.z-tagS, c0.w-tagS};
                    *(f32x4*)(lds_inp + lane * 4) = u;
                }
                if (__all(d0)) break;
                __builtin_amdgcn_s_sleep(1);
            }
        }
        __syncthreads();
        DOT(wA0, wB0, 1, lds_inp, 4, lds_h0 + (ps ^ 1) * H, bA0, bB0)
        __syncthreads();
        COMBINE(0, hg0 + ps * H, tagS)

        // ---------- phase B: layer 1 ----------
        POLLSTASH_H(hg0 + ps * H, lds_h0 + ps * H, tagS)
        __syncthreads();
        DOT(wA1, wB1, 4, lds_h0 + ps * H, 4, lds_h1 + (ps ^ 1) * H, bA1, bB1)
        __syncthreads();
        COMBINE(1, hg1 + ps * H, tagS)

        // ---------- phase C: layer 2 ----------
        POLLSTASH_H(hg1 + ps * H, lds_h1 + ps * H, tagS)
        __syncthreads();
        DOT(wA2, wB2, 4, lds_h1 + ps * H, 4, lds_h2 + (ps ^ 1) * H, bA2, bB2)
        __syncthreads();
        COMBINE(2, hg2 + ps * H, tagS)

        // ---------- phase D: gather h2 (next-step recurrent) + fc ----------
        POLLSTASH_H(hg2 + ps * H, lds_h2 + ps * H, tagS)
        __syncthreads();
        if (s + 1 >= L) {
            float2 pv = *(const float2*)(lds_h2 + ps * H + 2 * tid);
            float2 fw = *(const float2*)(lds_fc + 2 * tid);
            float a = waveReduce(pv.x * fw.x + pv.y * fw.y);
            if (lane == 0) red[w] = a;
            __syncthreads();
        }
        if (w == 7 && lane == 0) {
            float nxt;
            if (s + 1 < L) {
                nxt = lds_x[s + 1];
            } else {
                float sfc = red[0] + red[1] + red[2] + red[3]
                          + red[4] + red[5] + red[6] + red[7];
                nxt = sigf(sfc + bfc_b);
            }
            out[(size_t)b * T + s + 1] = nxt;
            stg1_sc(inp + b, nxt + tagf(s + 1));
        }
    }
#undef DOT
#undef COMBINE
#undef POLLSTASH_H
}

extern "C" void kernel_launch(void* const* d_in, const int* in_sizes, int n_in,
                              void* d_out, int out_size, void* d_ws, size_t ws_size,
                              hipStream_t stream) {
    const float* x    = (const float*)d_in[0];
    const float* h0   = (const float*)d_in[1];
    const float* c0   = (const float*)d_in[2];
    const float* Wih0 = (const float*)d_in[3];
    const float* Whh0 = (const float*)d_in[4];
    const float* Wih1 = (const float*)d_in[5];
    const float* Whh1 = (const float*)d_in[6];
    const float* Wih2 = (const float*)d_in[7];
    const float* Whh2 = (const float*)d_in[8];
    const float* bih  = (const float*)d_in[9];
    const float* bhh  = (const float*)d_in[10];
    const float* Wfc  = (const float*)d_in[11];
    const float* bfc  = (const float*)d_in[12];

    float* out = (float*)d_out;
    float* ws  = (float*)d_ws;

    int T = out_size / D;        // 2048
    int L = in_sizes[0] / D;     // 64

    ws_clear<<<1, 512, 0, stream>>>(ws);

    void* args[] = { &x, &h0, &c0, &Wih0, &Whh0, &Wih1, &Whh1, &Wih2, &Whh2,
                     &bih, &bhh, &Wfc, &bfc, &out, &ws, &T, &L };

    (void)hipLaunchCooperativeKernel((void*)rnn_reg6, dim3(NB), dim3(NT), args, 0, stream);
}

// Round 11
// 24448.169 us; speedup vs baseline: 1.0287x; 1.0121x over previous
//
#include <hip/hip_runtime.h>
#include <math.h>

#define H 1024
#define D 256
#define NB 256
#define NT 512
#define LW 64        // warmup (teacher-forced) length
#define STRIDE 32    // floats between chunks = 128B: one LLC line per block

typedef float f32x4 __attribute__((ext_vector_type(4)));

__device__ __forceinline__ float sigf(float v) { return 1.f / (1.f + __expf(-v)); }

__device__ __forceinline__ float waveReduce(float v) {
#pragma unroll
    for (int off = 32; off > 0; off >>= 1) v += __shfl_xor(v, off, 64);
    return v;
}

// LLC-coherent ops (sc0 sc1 bypass L1/L2) — no cache-maintenance fences needed.
__device__ __forceinline__ f32x4 ldg4_nw(const float* p) {   // issue only
    f32x4 r;
    asm volatile("global_load_dwordx4 %0, %1, off sc0 sc1" : "=v"(r) : "v"(p) : "memory");
    return r;
}
__device__ __forceinline__ float ldg1_nw(const float* p) {
    float r;
    asm volatile("global_load_dword %0, %1, off sc0 sc1" : "=v"(r) : "v"(p) : "memory");
    return r;
}
// waits with loaded values data-chained through (rule-18 safe)
__device__ __forceinline__ void vm_wait4(f32x4& a, f32x4& b, f32x4& c, f32x4& d) {
    asm volatile("s_waitcnt vmcnt(0)" : "+v"(a), "+v"(b), "+v"(c), "+v"(d) :: "memory");
    __builtin_amdgcn_sched_barrier(0);
}
__device__ __forceinline__ void vm_wait4f(float& a, float& b, float& c, float& d) {
    asm volatile("s_waitcnt vmcnt(0)" : "+v"(a), "+v"(b), "+v"(c), "+v"(d) :: "memory");
    __builtin_amdgcn_sched_barrier(0);
}
__device__ __forceinline__ void stg4_sc(float* p, f32x4 v) {
    asm volatile("global_store_dwordx4 %0, %1, off sc0 sc1" :: "v"(p), "v"(v) : "memory");
}
__device__ __forceinline__ void stg1_sc(float* p, float v) {
    asm volatile("global_store_dword %0, %1, off sc0 sc1" :: "v"(p), "v"(v) : "memory");
}

// Tags: |value| < 1 always; producer stores value + tag, tag = 8*(s&3)-12 in
// {-12,-4,4,12}. Valid iff |x - tag| < 2. Zero / 0xAA / stale / torn chunks
// can never false-validate (region spacing 8 >> threshold 2 + |v|<1).
__device__ __forceinline__ float tagf(int i) { return 8.0f * (float)(i & 3) - 12.0f; }
__device__ __forceinline__ bool vld4(f32x4 c, float tg) {
    float m = fmaxf(fmaxf(fabsf(c.x - tg), fabsf(c.y - tg)),
                    fmaxf(fabsf(c.z - tg), fabsf(c.w - tg)));
    return m < 2.0f;
}

// ---- static exchange buffers (module-allocated; no d_ws size dependence) ----
// region 0:       inp chunks  (1 float used per 32-float chunk)
// region 1+l*2+p: hg[layer l][ping-pong p] chunks (4 floats used per chunk)
#define EXN ((1 + 6) * NB * STRIDE)
__device__ float g_ex[EXN];

__global__ void ws_clear() {
    int i = blockIdx.x * blockDim.x + threadIdx.x;
    for (; i < EXN; i += gridDim.x * blockDim.x) g_ex[i] = 0.f;
}

__global__ __launch_bounds__(NT, 2) void rnn_reg8(
    const float* __restrict__ x, const float* __restrict__ h0in, const float* __restrict__ c0,
    const float* __restrict__ Wih0, const float* __restrict__ Whh0,
    const float* __restrict__ Wih1, const float* __restrict__ Whh1,
    const float* __restrict__ Wih2, const float* __restrict__ Whh2,
    const float* __restrict__ b_ih, const float* __restrict__ b_hh,
    const float* __restrict__ Wfc, const float* __restrict__ bfc,
    float* __restrict__ out, int T, int L)
{
    const int b = blockIdx.x;
    const int tid = threadIdx.x;
    const int w = tid >> 6;
    const int lane = tid & 63;
    const int gate = w & 3;          // i,f,g,o
    const int up = w >> 2;           // 0..1 -> unit pair
    const int u0 = b * 4 + 2 * up;
    const int r0 = gate * H + u0;
    const int r1 = r0 + 1;
    const int off = lane * 4;

    float* inpw = g_ex;

    __shared__ __align__(16) float lds_h0[2 * H], lds_h1[2 * H], lds_h2[2 * H];
    __shared__ __align__(16) float lds_fc[H];
    __shared__ __align__(16) float lds_inp[D];
    __shared__ float lds_x[LW];
    __shared__ float gate_buf[16];
    __shared__ float red[8];
    __shared__ float c_st[12];

    // ---- one-time: weights -> registers (2 rows/wave, 42 float4) ----
    float4 wA0[5], wB0[5], wA1[8], wB1[8], wA2[8], wB2[8];
    wA0[0] = *(const float4*)(Wih0 + (size_t)r0 * 256 + off);
    wB0[0] = *(const float4*)(Wih0 + (size_t)r1 * 256 + off);
#pragma unroll
    for (int j = 0; j < 4; ++j) {
        wA0[j + 1] = *(const float4*)(Whh0 + (size_t)r0 * H + j * 256 + off);
        wB0[j + 1] = *(const float4*)(Whh0 + (size_t)r1 * H + j * 256 + off);
        wA1[j]     = *(const float4*)(Wih1 + (size_t)r0 * H + j * 256 + off);
        wB1[j]     = *(const float4*)(Wih1 + (size_t)r1 * H + j * 256 + off);
        wA1[j + 4] = *(const float4*)(Whh1 + (size_t)r0 * H + j * 256 + off);
        wB1[j + 4] = *(const float4*)(Whh1 + (size_t)r1 * H + j * 256 + off);
        wA2[j]     = *(const float4*)(Wih2 + (size_t)r0 * H + j * 256 + off);
        wB2[j]     = *(const float4*)(Wih2 + (size_t)r1 * H + j * 256 + off);
        wA2[j + 4] = *(const float4*)(Whh2 + (size_t)r0 * H + j * 256 + off);
        wB2[j + 4] = *(const float4*)(Whh2 + (size_t)r1 * H + j * 256 + off);
    }
    const float bA0 = b_ih[r0] + b_hh[r0];
    const float bB0 = b_ih[r1] + b_hh[r1];
    const float bA1 = b_ih[4 * H + r0] + b_hh[4 * H + r0];
    const float bB1 = b_ih[4 * H + r1] + b_hh[4 * H + r1];
    const float bA2 = b_ih[8 * H + r0] + b_hh[8 * H + r0];
    const float bB2 = b_ih[8 * H + r1] + b_hh[8 * H + r1];
    const float bfc_b = bfc[b];

#define KA(v) asm volatile("" : "+v"(v.x), "+v"(v.y), "+v"(v.z), "+v"(v.w))
#pragma unroll
    for (int j = 0; j < 5; ++j) { KA(wA0[j]); KA(wB0[j]); }
#pragma unroll
    for (int j = 0; j < 8; ++j) { KA(wA1[j]); KA(wB1[j]); KA(wA2[j]); KA(wB2[j]); }
#undef KA

    // ---- prologue: initial states into LDS slot 1 (read by step 0) ----
    for (int i = tid; i < H; i += NT) {
        lds_fc[i]     = Wfc[(size_t)b * H + i];
        lds_h0[H + i] = h0in[i];
        lds_h1[H + i] = h0in[H + i];
        lds_h2[H + i] = h0in[2 * H + i];
    }
    if (tid < LW && tid < L) lds_x[tid] = x[(size_t)b * L + tid];
    if (tid < 12) c_st[tid] = c0[(tid >> 2) * H + b * 4 + (tid & 3)];
    if (tid == 0) {
        float v = x[(size_t)b * L];
        out[(size_t)b * T] = v;                       // out column 0
        stg1_sc(inpw + b * STRIDE, v + tagf(0));      // step-0 input
    }
    __syncthreads();

    // wave-0 poll+stash: 256 strided chunks -> LDS; loads double as data fetch.
    // First retry immediate, then s_sleep(8) backoff (bounds the read storm).
#define POLLH(SRC, DST, TG)                                                    \
    if (w == 0) {                                                              \
        const float* s_ = (SRC); float* d_ = (DST); const float tg_ = (TG);    \
        bool d0 = false, d1 = false, d2 = false, d3 = false;                   \
        int spin = 0;                                                          \
        for (;;) {                                                             \
            f32x4 c0 = {0,0,0,0}, c1 = c0, c2 = c0, c3 = c0;                   \
            if (!d0) c0 = ldg4_nw(s_ + lane * STRIDE);                         \
            if (!d1) c1 = ldg4_nw(s_ + (lane + 64) * STRIDE);                  \
            if (!d2) c2 = ldg4_nw(s_ + (lane + 128) * STRIDE);                 \
            if (!d3) c3 = ldg4_nw(s_ + (lane + 192) * STRIDE);                 \
            vm_wait4(c0, c1, c2, c3);                                          \
            if (!d0 && vld4(c0, tg_)) { d0 = true;                             \
                f32x4 u = {c0.x-tg_, c0.y-tg_, c0.z-tg_, c0.w-tg_};            \
                *(f32x4*)(d_ + lane * 4) = u; }                                \
            if (!d1 && vld4(c1, tg_)) { d1 = true;                             \
                f32x4 u = {c1.x-tg_, c1.y-tg_, c1.z-tg_, c1.w-tg_};            \
                *(f32x4*)(d_ + (lane + 64) * 4) = u; }                         \
            if (!d2 && vld4(c2, tg_)) { d2 = true;                             \
                f32x4 u = {c2.x-tg_, c2.y-tg_, c2.z-tg_, c2.w-tg_};            \
                *(f32x4*)(d_ + (lane + 128) * 4) = u; }                        \
            if (!d3 && vld4(c3, tg_)) { d3 = true;                             \
                f32x4 u = {c3.x-tg_, c3.y-tg_, c3.z-tg_, c3.w-tg_};            \
                *(f32x4*)(d_ + (lane + 192) * 4) = u; }                        \
            if (__all(d0 && d1 && d2 && d3)) break;                            \
            if (++spin > 1) __builtin_amdgcn_s_sleep(8);                       \
        }                                                                      \
    }

#define DOT(WA, WB, N1, P1, N2, P2, BA, BB)                                   \
    {                                                                         \
        float4 a0 = {0,0,0,0}, a1 = {0,0,0,0};                                \
        _Pragma("unroll")                                                     \
        for (int j = 0; j < N1; ++j) {                                        \
            float4 v = *(const float4*)((P1) + j * 256 + off);                \
            a0.x += WA[j].x*v.x; a0.y += WA[j].y*v.y;                         \
            a0.z += WA[j].z*v.z; a0.w += WA[j].w*v.w;                         \
            a1.x += WB[j].x*v.x; a1.y += WB[j].y*v.y;                         \
            a1.z += WB[j].z*v.z; a1.w += WB[j].w*v.w;                         \
        }                                                                     \
        _Pragma("unroll")                                                     \
        for (int j = 0; j < N2; ++j) {                                        \
            float4 v = *(const float4*)((P2) + j * 256 + off);                \
            a0.x += WA[N1+j].x*v.x; a0.y += WA[N1+j].y*v.y;                   \
            a0.z += WA[N1+j].z*v.z; a0.w += WA[N1+j].w*v.w;                   \
            a1.x += WB[N1+j].x*v.x; a1.y += WB[N1+j].y*v.y;                   \
            a1.z += WB[N1+j].z*v.z; a1.w += WB[N1+j].w*v.w;                   \
        }                                                                     \
        float s0 = waveReduce(a0.x + a0.y + a0.z + a0.w);                     \
        float s1 = waveReduce(a1.x + a1.y + a1.z + a1.w);                     \
        if (lane == 0) {                                                      \
            gate_buf[(2*up)*4 + gate]   = s0 + BA;                            \
            gate_buf[(2*up+1)*4 + gate] = s1 + BB;                            \
        }                                                                     \
    }

    // wave 7: combine gates, pack 4 h values + tag, single fire-and-forget store.
#define COMBINE(LIDX, HGPTR, TG)                                              \
    if (w == 7) {                                                             \
        float hn = 0.f;                                                       \
        if (lane < 4) {                                                       \
            float gi = gate_buf[lane*4+0], gf = gate_buf[lane*4+1];           \
            float gg = gate_buf[lane*4+2], go = gate_buf[lane*4+3];           \
            float cn = sigf(gf)*c_st[(LIDX)*4+lane] + sigf(gi)*tanhf(gg);     \
            c_st[(LIDX)*4+lane] = cn;                                         \
            hn = sigf(go)*tanhf(cn);                                          \
        }                                                                     \
        float v0=__shfl(hn,0), v1=__shfl(hn,1), v2=__shfl(hn,2), v3=__shfl(hn,3); \
        if (lane == 0) {                                                      \
            f32x4 pk = {v0+(TG), v1+(TG), v2+(TG), v3+(TG)};                  \
            stg4_sc((HGPTR) + b*STRIDE, pk);                                  \
        }                                                                     \
    }

    for (int s = 0; s < T - 1; ++s) {
        const int ps = s & 1;
        const float tagS = tagf(s);
        float* hg0 = g_ex + (1 + 0 * 2 + ps) * NB * STRIDE;
        float* hg1 = g_ex + (1 + 1 * 2 + ps) * NB * STRIDE;
        float* hg2 = g_ex + (1 + 2 * 2 + ps) * NB * STRIDE;

        // ---------- phase A: gather inp, layer 0 ----------
        if (w == 0) {
            bool e0 = false, e1 = false, e2 = false, e3 = false;
            int spin = 0;
            for (;;) {
                float c0 = 0.f, c1 = 0.f, c2 = 0.f, c3 = 0.f;
                if (!e0) c0 = ldg1_nw(inpw + lane * STRIDE);
                if (!e1) c1 = ldg1_nw(inpw + (lane + 64) * STRIDE);
                if (!e2) c2 = ldg1_nw(inpw + (lane + 128) * STRIDE);
                if (!e3) c3 = ldg1_nw(inpw + (lane + 192) * STRIDE);
                vm_wait4f(c0, c1, c2, c3);
                if (!e0 && fabsf(c0 - tagS) < 2.f) { e0 = true; lds_inp[lane]       = c0 - tagS; }
                if (!e1 && fabsf(c1 - tagS) < 2.f) { e1 = true; lds_inp[lane + 64]  = c1 - tagS; }
                if (!e2 && fabsf(c2 - tagS) < 2.f) { e2 = true; lds_inp[lane + 128] = c2 - tagS; }
                if (!e3 && fabsf(c3 - tagS) < 2.f) { e3 = true; lds_inp[lane + 192] = c3 - tagS; }
                if (__all(e0 && e1 && e2 && e3)) break;
                if (++spin > 1) __builtin_amdgcn_s_sleep(8);
            }
        }
        __syncthreads();
        DOT(wA0, wB0, 1, lds_inp, 4, lds_h0 + (ps ^ 1) * H, bA0, bB0)
        __syncthreads();
        COMBINE(0, hg0, tagS)

        // ---------- phase B: gather h0, layer 1 ----------
        POLLH(hg0, lds_h0 + ps * H, tagS)
        __syncthreads();
        DOT(wA1, wB1, 4, lds_h0 + ps * H, 4, lds_h1 + (ps ^ 1) * H, bA1, bB1)
        __syncthreads();
        COMBINE(1, hg1, tagS)

        // ---------- phase C: gather h1, layer 2 ----------
        POLLH(hg1, lds_h1 + ps * H, tagS)
        __syncthreads();
        DOT(wA2, wB2, 4, lds_h1 + ps * H, 4, lds_h2 + (ps ^ 1) * H, bA2, bB2)
        __syncthreads();
        COMBINE(2, hg2, tagS)

        // ---------- phase D: gather h2 (next-step recurrent) + fc ----------
        POLLH(hg2, lds_h2 + ps * H, tagS)
        __syncthreads();
        if (s + 1 >= L) {
            float2 pv = *(const float2*)(lds_h2 + ps * H + 2 * tid);
            float2 fw = *(const float2*)(lds_fc + 2 * tid);
            float a = waveReduce(pv.x * fw.x + pv.y * fw.y);
            if (lane == 0) red[w] = a;
            __syncthreads();
        }
        if (w == 7 && lane == 0) {
            float nxt;
            if (s + 1 < L) {
                nxt = lds_x[s + 1];
            } else {
                float sfc = red[0] + red[1] + red[2] + red[3]
                          + red[4] + red[5] + red[6] + red[7];
                nxt = sigf(sfc + bfc_b);
            }
            out[(size_t)b * T + s + 1] = nxt;
            stg1_sc(inpw + b * STRIDE, nxt + tagf(s + 1));
        }
    }
#undef DOT
#undef COMBINE
#undef POLLH
}

extern "C" void kernel_launch(void* const* d_in, const int* in_sizes, int n_in,
                              void* d_out, int out_size, void* d_ws, size_t ws_size,
                              hipStream_t stream) {
    const float* x    = (const float*)d_in[0];
    const float* h0   = (const float*)d_in[1];
    const float* c0   = (const float*)d_in[2];
    const float* Wih0 = (const float*)d_in[3];
    const float* Whh0 = (const float*)d_in[4];
    const float* Wih1 = (const float*)d_in[5];
    const float* Whh1 = (const float*)d_in[6];
    const float* Wih2 = (const float*)d_in[7];
    const float* Whh2 = (const float*)d_in[8];
    const float* bih  = (const float*)d_in[9];
    const float* bhh  = (const float*)d_in[10];
    const float* Wfc  = (const float*)d_in[11];
    const float* bfc  = (const float*)d_in[12];

    float* out = (float*)d_out;

    int T = out_size / D;        // 2048
    int L = in_sizes[0] / D;     // 64

    ws_clear<<<64, 256, 0, stream>>>();

    void* args[] = { &x, &h0, &c0, &Wih0, &Whh0, &Wih1, &Whh1, &Wih2, &Whh2,
                     &bih, &bhh, &Wfc, &bfc, &out, &T, &L };

    (void)hipLaunchCooperativeKernel((void*)rnn_reg8, dim3(NB), dim3(NT), args, 0, stream);
}